// Round 10
// baseline (607.366 us; speedup 1.0000x reference)
//
#include <hip/hip_runtime.h>
#include <hip/hip_bf16.h>

typedef __attribute__((ext_vector_type(8))) short bf16x8_t;   // 8 bf16 = 4 VGPRs (MFMA A/B frag)
typedef __attribute__((ext_vector_type(4))) float f32x4;      // MFMA C/D frag

#define S_LEN  2048
#define NB     2
#define NH     32
#define NKVH   8
#define HD     64
#define DMODEL 2048
#define SCALE  0.125f
#define CEXP   0.18033688f     // SCALE * log2(e)
#define THRRAW 44.0f           // defer-max threshold in raw-logit units (~8 exp2 units)

// async global->LDS, 16B per lane; lds dst is wave-uniform base + lane*16
__device__ __forceinline__ void gload16(const __hip_bfloat16* g, __hip_bfloat16* l) {
  __builtin_amdgcn_global_load_lds(
      (const __attribute__((address_space(1))) void*)g,
      (__attribute__((address_space(3))) void*)l, 16, 0, 0);
}

// XCD-aware bijective block swizzle (nwg % 8 == 0 for all our grids)
__device__ __forceinline__ int xcd_swz(int bid, int nwg) {
  return (bid & 7) * (nwg >> 3) + (bid >> 3);
}

// ---------------------------------------------------------------- fused fp32 -> bf16 (5 segments)
struct CvtSeg { const float* src; __hip_bfloat16* dst; int n4; };
struct CvtArgs { CvtSeg s[5]; };

__global__ __launch_bounds__(256) void cvt_all(CvtArgs a) {
  int i = blockIdx.x * blockDim.x + threadIdx.x;
#pragma unroll
  for (int k = 0; k < 5; ++k) {
    if (i < a.s[k].n4) {
      float4 v = ((const float4*)a.s[k].src)[i];
      __hip_bfloat16 o0 = __float2bfloat16(v.x), o1 = __float2bfloat16(v.y);
      __hip_bfloat16 o2 = __float2bfloat16(v.z), o3 = __float2bfloat16(v.w);
      ushort4 pk;
      pk.x = *(unsigned short*)&o0; pk.y = *(unsigned short*)&o1;
      pk.z = *(unsigned short*)&o2; pk.w = *(unsigned short*)&o3;
      ((ushort4*)a.s[k].dst)[i] = pk;
      return;
    }
    i -= a.s[k].n4;
  }
}

// ---------------------------------------------------------------- fused QKV projection + RoPE (2-phase dbuf)
__global__ __launch_bounds__(256)
void gemm_qkv(const __hip_bfloat16* __restrict__ A,
              const __hip_bfloat16* __restrict__ Wq,
              const __hip_bfloat16* __restrict__ Wk,
              const __hip_bfloat16* __restrict__ Wv,
              __hip_bfloat16* __restrict__ Qo,
              __hip_bfloat16* __restrict__ Ko,
              __hip_bfloat16* __restrict__ Vto,
              const float* __restrict__ cosb,
              const float* __restrict__ sinb)
{
  __shared__ __align__(16) __hip_bfloat16 As[2][128][32];
  __shared__ __align__(16) __hip_bfloat16 Bs[2][128][32];
  const int K = DMODEL;

  const int tid  = threadIdx.x;
  const int lane = tid & 63;
  const int w    = tid >> 6;
  const int wr   = (w >> 1) * 64;
  const int wc   = (w & 1) * 64;
  const int fr   = lane & 15;
  const int fg   = lane >> 4;

  // XCD swizzle (T1): contiguous swz-chunks per XCD -> A-panel L2 residency
  const int nwg = gridDim.x * gridDim.y;
  const int swz = xcd_swz(blockIdx.y * gridDim.x + blockIdx.x, nwg);
  const int bx  = swz % gridDim.x;
  const int by  = swz / gridDim.x;
  const int brow = by * 128;

  const int bc = bx * 128;
  const __hip_bfloat16* Bt; int bcol; int path;
  if (bc < 2048)      { Bt = Wq; bcol = bc;        path = 0; }
  else if (bc < 2560) { Bt = Wk; bcol = bc - 2048; path = 1; }
  else                { Bt = Wv; bcol = bc - 2560; path = 2; }

  const f32x4 fz = {0.f, 0.f, 0.f, 0.f};
  f32x4 acc[4][4];
#pragma unroll
  for (int i = 0; i < 4; ++i)
#pragma unroll
    for (int j = 0; j < 4; ++j) acc[i][j] = fz;

  const int lrow = lane >> 2;           // 0..15
  const int lcol = (lane & 3) * 8;      // 16B chunk
  const __hip_bfloat16* Ag = A  + (size_t)(brow + w * 32 + lrow) * K + lcol;
  const __hip_bfloat16* Bg = Bt + (size_t)(bcol + w * 32 + lrow) * K + lcol;

  auto stage = [&](int buf, int kt) {
    gload16(Ag + kt,                    &As[buf][w * 32][0]);
    gload16(Ag + (size_t)16 * K + kt,   &As[buf][w * 32 + 16][0]);
    gload16(Bg + kt,                    &Bs[buf][w * 32][0]);
    gload16(Bg + (size_t)16 * K + kt,   &Bs[buf][w * 32 + 16][0]);
  };

  stage(0, 0);
  __syncthreads();
  int cur = 0;
  for (int kt = 0; kt < K; kt += 32) {
    if (kt + 32 < K) stage(cur ^ 1, kt + 32);

    bf16x8_t af[4], bfr[4];
#pragma unroll
    for (int mi = 0; mi < 4; ++mi)
      af[mi] = *(const bf16x8_t*)&As[cur][wr + mi * 16 + fr][fg * 8];
#pragma unroll
    for (int ni = 0; ni < 4; ++ni)
      bfr[ni] = *(const bf16x8_t*)&Bs[cur][wc + ni * 16 + fr][fg * 8];
#pragma unroll
    for (int mi = 0; mi < 4; ++mi)
#pragma unroll
      for (int ni = 0; ni < 4; ++ni)
        acc[mi][ni] = __builtin_amdgcn_mfma_f32_16x16x32_bf16(af[mi], bfr[ni], acc[mi][ni], 0, 0, 0);

    __syncthreads();
    cur ^= 1;
  }

  if (path == 2) {
#pragma unroll
    for (int mi = 0; mi < 4; ++mi) {
#pragma unroll
      for (int ni = 0; ni < 4; ++ni) {
        const int row0 = brow + wr + mi * 16 + fg * 4;
        const int col  = bcol + wc + ni * 16 + fr;
        const int b = row0 >> 11, s = row0 & 2047;
        const int kvh = col >> 6, d = col & 63;
        __hip_bfloat16 v0 = __float2bfloat16(acc[mi][ni][0]);
        __hip_bfloat16 v1 = __float2bfloat16(acc[mi][ni][1]);
        __hip_bfloat16 v2 = __float2bfloat16(acc[mi][ni][2]);
        __hip_bfloat16 v3 = __float2bfloat16(acc[mi][ni][3]);
        ushort4 pk;
        pk.x = *(unsigned short*)&v0; pk.y = *(unsigned short*)&v1;
        pk.z = *(unsigned short*)&v2; pk.w = *(unsigned short*)&v3;
        *(ushort4*)&Vto[(((size_t)b * NKVH + kvh) * HD + d) * S_LEN + s] = pk;
      }
    }
  } else {
    __hip_bfloat16* C = (path == 0) ? Qo : Ko;
    const int N = (path == 0) ? (NH * HD) : (NKVH * HD);
#pragma unroll
    for (int mi = 0; mi < 4; ++mi) {
#pragma unroll
      for (int r = 0; r < 4; ++r) {
        const int row = brow + wr + mi * 16 + fg * 4 + r;
#pragma unroll
        for (int ni = 0; ni < 2; ++ni) {   // ni pairs with ni+2 : (d, d+32) same head, same lane
          const int colL = bcol + wc + ni * 16 + fr;
          const int d    = (colL & 63);    // < 32
          const float c  = cosb[(size_t)row * HD + d];
          const float sn = sinb[(size_t)row * HD + d];
          const float v0 = acc[mi][ni][r];
          const float v1 = acc[mi][ni + 2][r];
          C[(size_t)row * N + colL]      = __float2bfloat16(v0 * c - v1 * sn);
          C[(size_t)row * N + colL + 32] = __float2bfloat16(v1 * c + v0 * sn);
        }
      }
    }
  }
}

// ---------------------------------------------------------------- output projection (2-phase dbuf, fp32 out)
__global__ __launch_bounds__(256)
void gemm_o(const __hip_bfloat16* __restrict__ A,
            const __hip_bfloat16* __restrict__ Bt,
            float* __restrict__ C)
{
  __shared__ __align__(16) __hip_bfloat16 As[2][128][32];
  __shared__ __align__(16) __hip_bfloat16 Bs[2][128][32];
  const int K = DMODEL, N = DMODEL;

  const int tid  = threadIdx.x;
  const int lane = tid & 63;
  const int w    = tid >> 6;
  const int wr   = (w >> 1) * 64;
  const int wc   = (w & 1) * 64;
  const int fr   = lane & 15;
  const int fg   = lane >> 4;

  const int nwg = gridDim.x * gridDim.y;
  const int swz = xcd_swz(blockIdx.y * gridDim.x + blockIdx.x, nwg);
  const int bx  = swz % gridDim.x;
  const int by  = swz / gridDim.x;
  const int brow = by * 128;
  const int bcol = bx * 128;

  const f32x4 fz = {0.f, 0.f, 0.f, 0.f};
  f32x4 acc[4][4];
#pragma unroll
  for (int i = 0; i < 4; ++i)
#pragma unroll
    for (int j = 0; j < 4; ++j) acc[i][j] = fz;

  const int lrow = lane >> 2;
  const int lcol = (lane & 3) * 8;
  const __hip_bfloat16* Ag = A  + (size_t)(brow + w * 32 + lrow) * K + lcol;
  const __hip_bfloat16* Bg = Bt + (size_t)(bcol + w * 32 + lrow) * K + lcol;

  auto stage = [&](int buf, int kt) {
    gload16(Ag + kt,                  &As[buf][w * 32][0]);
    gload16(Ag + (size_t)16 * K + kt, &As[buf][w * 32 + 16][0]);
    gload16(Bg + kt,                  &Bs[buf][w * 32][0]);
    gload16(Bg + (size_t)16 * K + kt, &Bs[buf][w * 32 + 16][0]);
  };

  stage(0, 0);
  __syncthreads();
  int cur = 0;
  for (int kt = 0; kt < K; kt += 32) {
    if (kt + 32 < K) stage(cur ^ 1, kt + 32);

    bf16x8_t af[4], bfr[4];
#pragma unroll
    for (int mi = 0; mi < 4; ++mi)
      af[mi] = *(const bf16x8_t*)&As[cur][wr + mi * 16 + fr][fg * 8];
#pragma unroll
    for (int ni = 0; ni < 4; ++ni)
      bfr[ni] = *(const bf16x8_t*)&Bs[cur][wc + ni * 16 + fr][fg * 8];
#pragma unroll
    for (int mi = 0; mi < 4; ++mi)
#pragma unroll
      for (int ni = 0; ni < 4; ++ni)
        acc[mi][ni] = __builtin_amdgcn_mfma_f32_16x16x32_bf16(af[mi], bfr[ni], acc[mi][ni], 0, 0, 0);

    __syncthreads();
    cur ^= 1;
  }

#pragma unroll
  for (int mi = 0; mi < 4; ++mi)
#pragma unroll
    for (int ni = 0; ni < 4; ++ni) {
      const int row0 = brow + wr + mi * 16 + fg * 4;
      const int col  = bcol + wc + ni * 16 + fr;
#pragma unroll
      for (int r = 0; r < 4; ++r)
        C[(size_t)(row0 + r) * N + col] = acc[mi][ni][r];
    }
}

// ---------------------------------------------------------------- flash attention (causal, GQA)
// Barrier-free: K/V fragments read DIRECTLY from global (L2/L3-resident; 8 MB unique).
// 8 waves x 16 q-rows, each wave loops over only ITS OWN active key tiles.
// LDS = per-wave P buffer only (18.4 KB). XCD swizzle groups kvh per XCD L2.
__global__ __launch_bounds__(512, 4)
void attn_kernel(const __hip_bfloat16* __restrict__ Q, const __hip_bfloat16* __restrict__ K,
                 const __hip_bfloat16* __restrict__ Vt, __hip_bfloat16* __restrict__ O)
{
  __shared__ __align__(16) __hip_bfloat16 Ps[8][16][72];   // per-wave P, padded

  const int lane = threadIdx.x & 63;
  const int w    = threadIdx.x >> 6;       // 0..7
  const int fr   = lane & 15;
  const int fg   = lane >> 4;

  // XCD swizzle: 128 consecutive swz-blocks per XCD = 2 kvh groups (1 MB K/V) per XCD L2
  const int nwg = gridDim.x * gridDim.y;   // 16 x 64 = 1024
  const int swz = xcd_swz(blockIdx.y * gridDim.x + blockIdx.x, nwg);
  const int bx  = swz & 15;
  const int bh  = swz >> 4;
  const int b    = bh >> 5;
  const int h    = bh & 31;
  const int kvh  = h >> 2;
  const int qt     = 15 - bx;              // LPT: heavy blocks first within each XCD chunk
  const int qbase  = qt * 128;
  const int base_s = qbase + w * 16;       // this wave's first q-row
  const int KSTR   = NKVH * HD;            // 512

  const __hip_bfloat16* Qg = Q + ((size_t)(b * S_LEN + qbase)) * DMODEL + h * HD;
  const __hip_bfloat16* Kg = K + (size_t)b * S_LEN * KSTR + kvh * HD;
  const __hip_bfloat16* Vg = Vt + ((size_t)(b * NKVH + kvh)) * HD * S_LEN;

  // Q fragments: 16 q-rows x 64 feat per wave (B-operand, col q = fr)
  bf16x8_t qf[2];
#pragma unroll
  for (int kk = 0; kk < 2; ++kk)
    qf[kk] = *(const bf16x8_t*)(Qg + (size_t)(w * 16 + fr) * DMODEL + kk * 32 + fg * 8);

  const f32x4 fz = {0.f, 0.f, 0.f, 0.f};
  f32x4 acc[4];
#pragma unroll
  for (int i = 0; i < 4; ++i) acc[i] = fz;
  float m_ = -1e30f;     // raw-logit running max (uniform across the 4 fg lanes of q=fr)
  float l_ = 0.f;        // per-lane partial sum; reduced across fg in epilogue

  const int NTw = ((base_s + 15) >> 6) + 1;   // only this wave's active tiles
  for (int t = 0; t < NTw; ++t) {
    const int kt = t * 64;

    // K fragments direct from global: rows kt + c*16 + fr, feat chunks fg*8 / 32+fg*8
    const __hip_bfloat16* Kt = Kg + (size_t)(kt + fr) * KSTR + fg * 8;
    bf16x8_t k0[4], k1[4];
#pragma unroll
    for (int c = 0; c < 4; ++c) {
      k0[c] = *(const bf16x8_t*)(Kt + (size_t)(c * 16) * KSTR);
      k1[c] = *(const bf16x8_t*)(Kt + (size_t)(c * 16) * KSTR + 32);
    }

    // QK^T swapped: rows = keys, col = q = fr
    f32x4 sc[4];
#pragma unroll
    for (int c = 0; c < 4; ++c) {
      sc[c] = __builtin_amdgcn_mfma_f32_16x16x32_bf16(k0[c], qf[0], fz, 0, 0, 0);
      sc[c] = __builtin_amdgcn_mfma_f32_16x16x32_bf16(k1[c], qf[1], sc[c], 0, 0, 0);
    }

    // V fragments issued early (independent; latency hides under softmax)
    const __hip_bfloat16* Vp = Vg + (size_t)fr * S_LEN + kt + fg * 8;
    bf16x8_t v0[4], v1[4];
#pragma unroll
    for (int fc = 0; fc < 4; ++fc) {
      v0[fc] = *(const bf16x8_t*)(Vp + (size_t)(fc * 16) * S_LEN);
      v1[fc] = *(const bf16x8_t*)(Vp + (size_t)(fc * 16) * S_LEN + 32);
    }

    // raw-domain max over own 16 keys (mask only in diagonal tiles)
    float p[4][4];
    float tm = -3.0e38f;
    if (kt + 63 > base_s) {
#pragma unroll
      for (int c = 0; c < 4; ++c)
#pragma unroll
        for (int r = 0; r < 4; ++r) {
          float v = sc[c][r];
          if (kt + c * 16 + fg * 4 + r > base_s + fr) v = -3.0e38f;
          p[c][r] = v; tm = fmaxf(tm, v);
        }
    } else {
#pragma unroll
      for (int c = 0; c < 4; ++c)
#pragma unroll
        for (int r = 0; r < 4; ++r) { p[c][r] = sc[c][r]; tm = fmaxf(tm, sc[c][r]); }
    }
    tm = fmaxf(tm, __shfl_xor(tm, 16));
    tm = fmaxf(tm, __shfl_xor(tm, 32));   // tm uniform across fg for each q=fr

    // defer-max: rescale only when the max actually grew past threshold
    if (!__all(tm <= m_ + THRRAW)) {
      const float mnew = fmaxf(m_, tm);
      const float sf = exp2f((m_ - mnew) * CEXP);
      m_ = mnew;
      l_ *= sf;
      float sfv[4];
#pragma unroll
      for (int r = 0; r < 4; ++r) sfv[r] = __shfl(sf, fg * 4 + r);
#pragma unroll
      for (int fc = 0; fc < 4; ++fc)
#pragma unroll
        for (int r = 0; r < 4; ++r) acc[fc][r] *= sfv[r];
    }

    // p = exp2((raw - m) * SCALE*log2e); per-lane partial l
    float ts = 0.f;
#pragma unroll
    for (int c = 0; c < 4; ++c)
#pragma unroll
      for (int r = 0; r < 4; ++r) {
        p[c][r] = exp2f((p[c][r] - m_) * CEXP);
        ts += p[c][r];
      }
    l_ += ts;

    // P -> per-wave LDS [q][key], 8B packed stores (cross-fg redistribution)
#pragma unroll
    for (int c = 0; c < 4; ++c) {
      __hip_bfloat16 b0 = __float2bfloat16(p[c][0]);
      __hip_bfloat16 b1 = __float2bfloat16(p[c][1]);
      __hip_bfloat16 b2 = __float2bfloat16(p[c][2]);
      __hip_bfloat16 b3 = __float2bfloat16(p[c][3]);
      ushort4 pk;
      pk.x = *(unsigned short*)&b0; pk.y = *(unsigned short*)&b1;
      pk.z = *(unsigned short*)&b2; pk.w = *(unsigned short*)&b3;
      *(ushort4*)&Ps[w][fr][c * 16 + fg * 4] = pk;
    }

    // PV: A = P (row q = fr), B = V (col d = fr)
#pragma unroll
    for (int kk = 0; kk < 2; ++kk) {
      bf16x8_t pa = *(const bf16x8_t*)&Ps[w][fr][kk * 32 + fg * 8];
#pragma unroll
      for (int fc = 0; fc < 4; ++fc) {
        bf16x8_t vf = (kk == 0) ? v0[fc] : v1[fc];
        acc[fc] = __builtin_amdgcn_mfma_f32_16x16x32_bf16(pa, vf, acc[fc], 0, 0, 0);
      }
    }
  }

  // epilogue: finish l reduce (across fg), then normalize
  l_ += __shfl_xor(l_, 16);
  l_ += __shfl_xor(l_, 32);
  float lv[4];
#pragma unroll
  for (int r = 0; r < 4; ++r) lv[r] = __builtin_amdgcn_rcpf(__shfl(l_, fg * 4 + r));
#pragma unroll
  for (int fc = 0; fc < 4; ++fc)
#pragma unroll
    for (int r = 0; r < 4; ++r) {
      const size_t row = (size_t)(b * S_LEN + base_s + fg * 4 + r);
      O[row * DMODEL + h * HD + fc * 16 + fr] = __float2bfloat16(acc[fc][r] * lv[r]);
    }
}

// ---------------------------------------------------------------- launch
extern "C" void kernel_launch(void* const* d_in, const int* in_sizes, int n_in,
                              void* d_out, int out_size, void* d_ws, size_t ws_size,
                              hipStream_t stream)
{
  const float* x    = (const float*)d_in[0];
  const float* cosb = (const float*)d_in[1];
  const float* sinb = (const float*)d_in[2];
  const float* Wq   = (const float*)d_in[3];
  const float* Wk   = (const float*)d_in[4];
  const float* Wv   = (const float*)d_in[5];
  const float* Wo   = (const float*)d_in[6];
  float* out = (float*)d_out;

  char* p = (char*)d_ws;
  __hip_bfloat16* x_bf    = (__hip_bfloat16*)p; p += (size_t)NB * S_LEN * DMODEL * 2;
  __hip_bfloat16* Wq_bf   = (__hip_bfloat16*)p; p += (size_t)NH * HD * DMODEL * 2;
  __hip_bfloat16* Wk_bf   = (__hip_bfloat16*)p; p += (size_t)NKVH * HD * DMODEL * 2;
  __hip_bfloat16* Wv_bf   = (__hip_bfloat16*)p; p += (size_t)NKVH * HD * DMODEL * 2;
  __hip_bfloat16* Wo_bf   = (__hip_bfloat16*)p; p += (size_t)DMODEL * NH * HD * 2;
  __hip_bfloat16* Q_bf    = (__hip_bfloat16*)p; p += (size_t)NB * S_LEN * NH * HD * 2;
  __hip_bfloat16* K_bf    = (__hip_bfloat16*)p; p += (size_t)NB * S_LEN * NKVH * HD * 2;
  __hip_bfloat16* Vt_bf   = (__hip_bfloat16*)p; p += (size_t)NB * NKVH * HD * S_LEN * 2;
  __hip_bfloat16* attn_bf = (__hip_bfloat16*)p; p += (size_t)NB * S_LEN * NH * HD * 2;

  CvtArgs ca;
  ca.s[0] = { x,  x_bf,  (int)((size_t)NB * S_LEN * DMODEL / 4) };
  ca.s[1] = { Wq, Wq_bf, (int)((size_t)NH * HD * DMODEL / 4) };
  ca.s[2] = { Wk, Wk_bf, (int)((size_t)NKVH * HD * DMODEL / 4) };
  ca.s[3] = { Wv, Wv_bf, (int)((size_t)NKVH * HD * DMODEL / 4) };
  ca.s[4] = { Wo, Wo_bf, (int)((size_t)DMODEL * NH * HD / 4) };
  int total4 = ca.s[0].n4 + ca.s[1].n4 + ca.s[2].n4 + ca.s[3].n4 + ca.s[4].n4;
  cvt_all<<<(total4 + 255) / 256, 256, 0, stream>>>(ca);

  gemm_qkv<<<dim3(3072 / 128, (NB * S_LEN) / 128), dim3(256), 0, stream>>>(
      x_bf, Wq_bf, Wk_bf, Wv_bf, Q_bf, K_bf, Vt_bf, cosb, sinb);

  attn_kernel<<<dim3(S_LEN / 128, NB * NH), dim3(512), 0, stream>>>(Q_bf, K_bf, Vt_bf, attn_bf);

  gemm_o<<<dim3(DMODEL / 128, (NB * S_LEN) / 128), dim3(256), 0, stream>>>(attn_bf, Wo_bf, out);
}

// Round 12
// 388.261 us; speedup vs baseline: 1.5643x; 1.5643x over previous
//
#include <hip/hip_runtime.h>
#include <hip/hip_bf16.h>

typedef __attribute__((ext_vector_type(8))) short bf16x8_t;   // 8 bf16 = 4 VGPRs (MFMA A/B frag)
typedef __attribute__((ext_vector_type(4))) float f32x4;      // MFMA C/D frag

#define S_LEN  2048
#define NB     2
#define NH     32
#define NKVH   8
#define HD     64
#define DMODEL 2048
#define SCALE  0.125f
#define CEXP   0.18033688f     // SCALE * log2(e)
#define THRRAW 44.0f           // defer-max threshold in raw-logit units (~8 exp2 units)

// async global->LDS, 16B per lane; lds dst is wave-uniform base + lane*16
__device__ __forceinline__ void gload16(const __hip_bfloat16* g, __hip_bfloat16* l) {
  __builtin_amdgcn_global_load_lds(
      (const __attribute__((address_space(1))) void*)g,
      (__attribute__((address_space(3))) void*)l, 16, 0, 0);
}

// XCD-aware bijective block swizzle (nwg % 8 == 0 for all our grids)
__device__ __forceinline__ int xcd_swz(int bid, int nwg) {
  return (bid & 7) * (nwg >> 3) + (bid >> 3);
}

// ---------------------------------------------------------------- fused fp32 -> bf16 (5 segments)
struct CvtSeg { const float* src; __hip_bfloat16* dst; int n4; };
struct CvtArgs { CvtSeg s[5]; };

__global__ __launch_bounds__(256) void cvt_all(CvtArgs a) {
  int i = blockIdx.x * blockDim.x + threadIdx.x;
#pragma unroll
  for (int k = 0; k < 5; ++k) {
    if (i < a.s[k].n4) {
      float4 v = ((const float4*)a.s[k].src)[i];
      __hip_bfloat16 o0 = __float2bfloat16(v.x), o1 = __float2bfloat16(v.y);
      __hip_bfloat16 o2 = __float2bfloat16(v.z), o3 = __float2bfloat16(v.w);
      ushort4 pk;
      pk.x = *(unsigned short*)&o0; pk.y = *(unsigned short*)&o1;
      pk.z = *(unsigned short*)&o2; pk.w = *(unsigned short*)&o3;
      ((ushort4*)a.s[k].dst)[i] = pk;
      return;
    }
    i -= a.s[k].n4;
  }
}

// ---------------------------------------------------------------- fused QKV projection + RoPE (2-phase dbuf)
__global__ __launch_bounds__(256)
void gemm_qkv(const __hip_bfloat16* __restrict__ A,
              const __hip_bfloat16* __restrict__ Wq,
              const __hip_bfloat16* __restrict__ Wk,
              const __hip_bfloat16* __restrict__ Wv,
              __hip_bfloat16* __restrict__ Qo,
              __hip_bfloat16* __restrict__ Ko,
              __hip_bfloat16* __restrict__ Vto,
              const float* __restrict__ cosb,
              const float* __restrict__ sinb)
{
  __shared__ __align__(16) __hip_bfloat16 As[2][128][32];
  __shared__ __align__(16) __hip_bfloat16 Bs[2][128][32];
  const int K = DMODEL;

  const int tid  = threadIdx.x;
  const int lane = tid & 63;
  const int w    = tid >> 6;
  const int wr   = (w >> 1) * 64;
  const int wc   = (w & 1) * 64;
  const int fr   = lane & 15;
  const int fg   = lane >> 4;

  // XCD swizzle (T1): contiguous swz-chunks per XCD -> A-panel L2 residency
  const int nwg = gridDim.x * gridDim.y;
  const int swz = xcd_swz(blockIdx.y * gridDim.x + blockIdx.x, nwg);
  const int bx  = swz % gridDim.x;
  const int by  = swz / gridDim.x;
  const int brow = by * 128;

  const int bc = bx * 128;
  const __hip_bfloat16* Bt; int bcol; int path;
  if (bc < 2048)      { Bt = Wq; bcol = bc;        path = 0; }
  else if (bc < 2560) { Bt = Wk; bcol = bc - 2048; path = 1; }
  else                { Bt = Wv; bcol = bc - 2560; path = 2; }

  const f32x4 fz = {0.f, 0.f, 0.f, 0.f};
  f32x4 acc[4][4];
#pragma unroll
  for (int i = 0; i < 4; ++i)
#pragma unroll
    for (int j = 0; j < 4; ++j) acc[i][j] = fz;

  const int lrow = lane >> 2;           // 0..15
  const int lcol = (lane & 3) * 8;      // 16B chunk
  const __hip_bfloat16* Ag = A  + (size_t)(brow + w * 32 + lrow) * K + lcol;
  const __hip_bfloat16* Bg = Bt + (size_t)(bcol + w * 32 + lrow) * K + lcol;

  auto stage = [&](int buf, int kt) {
    gload16(Ag + kt,                    &As[buf][w * 32][0]);
    gload16(Ag + (size_t)16 * K + kt,   &As[buf][w * 32 + 16][0]);
    gload16(Bg + kt,                    &Bs[buf][w * 32][0]);
    gload16(Bg + (size_t)16 * K + kt,   &Bs[buf][w * 32 + 16][0]);
  };

  stage(0, 0);
  __syncthreads();
  int cur = 0;
  for (int kt = 0; kt < K; kt += 32) {
    if (kt + 32 < K) stage(cur ^ 1, kt + 32);

    bf16x8_t af[4], bfr[4];
#pragma unroll
    for (int mi = 0; mi < 4; ++mi)
      af[mi] = *(const bf16x8_t*)&As[cur][wr + mi * 16 + fr][fg * 8];
#pragma unroll
    for (int ni = 0; ni < 4; ++ni)
      bfr[ni] = *(const bf16x8_t*)&Bs[cur][wc + ni * 16 + fr][fg * 8];
#pragma unroll
    for (int mi = 0; mi < 4; ++mi)
#pragma unroll
      for (int ni = 0; ni < 4; ++ni)
        acc[mi][ni] = __builtin_amdgcn_mfma_f32_16x16x32_bf16(af[mi], bfr[ni], acc[mi][ni], 0, 0, 0);

    __syncthreads();
    cur ^= 1;
  }

  if (path == 2) {
#pragma unroll
    for (int mi = 0; mi < 4; ++mi) {
#pragma unroll
      for (int ni = 0; ni < 4; ++ni) {
        const int row0 = brow + wr + mi * 16 + fg * 4;
        const int col  = bcol + wc + ni * 16 + fr;
        const int b = row0 >> 11, s = row0 & 2047;
        const int kvh = col >> 6, d = col & 63;
        __hip_bfloat16 v0 = __float2bfloat16(acc[mi][ni][0]);
        __hip_bfloat16 v1 = __float2bfloat16(acc[mi][ni][1]);
        __hip_bfloat16 v2 = __float2bfloat16(acc[mi][ni][2]);
        __hip_bfloat16 v3 = __float2bfloat16(acc[mi][ni][3]);
        ushort4 pk;
        pk.x = *(unsigned short*)&v0; pk.y = *(unsigned short*)&v1;
        pk.z = *(unsigned short*)&v2; pk.w = *(unsigned short*)&v3;
        *(ushort4*)&Vto[(((size_t)b * NKVH + kvh) * HD + d) * S_LEN + s] = pk;
      }
    }
  } else {
    __hip_bfloat16* C = (path == 0) ? Qo : Ko;
    const int N = (path == 0) ? (NH * HD) : (NKVH * HD);
#pragma unroll
    for (int mi = 0; mi < 4; ++mi) {
#pragma unroll
      for (int r = 0; r < 4; ++r) {
        const int row = brow + wr + mi * 16 + fg * 4 + r;
#pragma unroll
        for (int ni = 0; ni < 2; ++ni) {   // ni pairs with ni+2 : (d, d+32) same head, same lane
          const int colL = bcol + wc + ni * 16 + fr;
          const int d    = (colL & 63);    // < 32
          const float c  = cosb[(size_t)row * HD + d];
          const float sn = sinb[(size_t)row * HD + d];
          const float v0 = acc[mi][ni][r];
          const float v1 = acc[mi][ni + 2][r];
          C[(size_t)row * N + colL]      = __float2bfloat16(v0 * c - v1 * sn);
          C[(size_t)row * N + colL + 32] = __float2bfloat16(v1 * c + v0 * sn);
        }
      }
    }
  }
}

// ---------------------------------------------------------------- output projection (2-phase dbuf, fp32 out)
__global__ __launch_bounds__(256)
void gemm_o(const __hip_bfloat16* __restrict__ A,
            const __hip_bfloat16* __restrict__ Bt,
            float* __restrict__ C)
{
  __shared__ __align__(16) __hip_bfloat16 As[2][128][32];
  __shared__ __align__(16) __hip_bfloat16 Bs[2][128][32];
  const int K = DMODEL, N = DMODEL;

  const int tid  = threadIdx.x;
  const int lane = tid & 63;
  const int w    = tid >> 6;
  const int wr   = (w >> 1) * 64;
  const int wc   = (w & 1) * 64;
  const int fr   = lane & 15;
  const int fg   = lane >> 4;

  const int nwg = gridDim.x * gridDim.y;
  const int swz = xcd_swz(blockIdx.y * gridDim.x + blockIdx.x, nwg);
  const int bx  = swz % gridDim.x;
  const int by  = swz / gridDim.x;
  const int brow = by * 128;
  const int bcol = bx * 128;

  const f32x4 fz = {0.f, 0.f, 0.f, 0.f};
  f32x4 acc[4][4];
#pragma unroll
  for (int i = 0; i < 4; ++i)
#pragma unroll
    for (int j = 0; j < 4; ++j) acc[i][j] = fz;

  const int lrow = lane >> 2;
  const int lcol = (lane & 3) * 8;
  const __hip_bfloat16* Ag = A  + (size_t)(brow + w * 32 + lrow) * K + lcol;
  const __hip_bfloat16* Bg = Bt + (size_t)(bcol + w * 32 + lrow) * K + lcol;

  auto stage = [&](int buf, int kt) {
    gload16(Ag + kt,                  &As[buf][w * 32][0]);
    gload16(Ag + (size_t)16 * K + kt, &As[buf][w * 32 + 16][0]);
    gload16(Bg + kt,                  &Bs[buf][w * 32][0]);
    gload16(Bg + (size_t)16 * K + kt, &Bs[buf][w * 32 + 16][0]);
  };

  stage(0, 0);
  __syncthreads();
  int cur = 0;
  for (int kt = 0; kt < K; kt += 32) {
    if (kt + 32 < K) stage(cur ^ 1, kt + 32);

    bf16x8_t af[4], bfr[4];
#pragma unroll
    for (int mi = 0; mi < 4; ++mi)
      af[mi] = *(const bf16x8_t*)&As[cur][wr + mi * 16 + fr][fg * 8];
#pragma unroll
    for (int ni = 0; ni < 4; ++ni)
      bfr[ni] = *(const bf16x8_t*)&Bs[cur][wc + ni * 16 + fr][fg * 8];
#pragma unroll
    for (int mi = 0; mi < 4; ++mi)
#pragma unroll
      for (int ni = 0; ni < 4; ++ni)
        acc[mi][ni] = __builtin_amdgcn_mfma_f32_16x16x32_bf16(af[mi], bfr[ni], acc[mi][ni], 0, 0, 0);

    __syncthreads();
    cur ^= 1;
  }

#pragma unroll
  for (int mi = 0; mi < 4; ++mi)
#pragma unroll
    for (int ni = 0; ni < 4; ++ni) {
      const int row0 = brow + wr + mi * 16 + fg * 4;
      const int col  = bcol + wc + ni * 16 + fr;
#pragma unroll
      for (int r = 0; r < 4; ++r)
        C[(size_t)(row0 + r) * N + col] = acc[mi][ni][r];
    }
}

// ---------------------------------------------------------------- flash attention (causal, GQA)
// QBLK=256: 8 waves x 32 q-rows (two 16-row subtiles/wave, sequential). KVBLK=64,
// dbuf K/V via global_load_lds, XOR-swizzled via pre-swizzled global source (rule 21).
// 1 barrier/tile; staged bytes & barriers PER Q-ROW are half of the QBLK=128 version.
__global__ __launch_bounds__(512, 4)
void attn_kernel(const __hip_bfloat16* __restrict__ Q, const __hip_bfloat16* __restrict__ K,
                 const __hip_bfloat16* __restrict__ Vt, __hip_bfloat16* __restrict__ O)
{
  __shared__ __align__(16) __hip_bfloat16 Ks[2][64][64];
  __shared__ __align__(16) __hip_bfloat16 Vs[2][64][64];
  __shared__ __align__(16) __hip_bfloat16 Ps[8][16][72];   // per-wave P (one subtile at a time)

  const int lane = threadIdx.x & 63;
  const int w    = threadIdx.x >> 6;       // 0..7
  const int fr   = lane & 15;
  const int fg   = lane >> 4;
  const int r8   = lane >> 3;              // stage: row within 8-row chunk
  const int j8   = lane & 7;               // stage: 16B slot within row
  const int bh   = blockIdx.y;
  const int b    = bh >> 5;
  const int h    = bh & 31;
  const int kvh  = h >> 2;
  const int qt    = gridDim.x - 1 - blockIdx.x;   // LPT: heavy blocks first
  const int qbase = qt * 256;
  const int wbase = qbase + w * 32;        // this wave's first q-row (32 rows)

  const __hip_bfloat16* Qg = Q + ((size_t)(b * S_LEN + qbase)) * DMODEL + h * HD;
  const __hip_bfloat16* Kg = K + (size_t)b * S_LEN * (NKVH * HD) + kvh * HD;
  const __hip_bfloat16* Vg = Vt + ((size_t)(b * NKVH + kvh)) * HD * S_LEN;

  // Q fragments: 2 subtiles x 16 q-rows x 64 feat (B-operand, col q = fr)
  bf16x8_t qf[2][2];
#pragma unroll
  for (int s = 0; s < 2; ++s)
#pragma unroll
    for (int kk = 0; kk < 2; ++kk)
      qf[s][kk] = *(const bf16x8_t*)(Qg + (size_t)(w * 32 + s * 16 + fr) * DMODEL + kk * 32 + fg * 8);

  const f32x4 fz = {0.f, 0.f, 0.f, 0.f};
  f32x4 acc[2][4];
#pragma unroll
  for (int s = 0; s < 2; ++s)
#pragma unroll
    for (int i = 0; i < 4; ++i) acc[s][i] = fz;
  float m_[2] = {-1e30f, -1e30f};   // raw-logit running max per subtile
  float l_[2] = {0.f, 0.f};         // per-lane partial sums

  // waves 0-3 stage K rows, waves 4-7 stage V rows; source pre-swizzled (chunk j8^r8)
  auto stage = [&](int buf, int kt) {
    const int rb = (w & 3) * 16;
    if (w < 4) {
      gload16(Kg + (size_t)(kt + rb + r8)     * (NKVH * HD) + (j8 ^ r8) * 8, &Ks[buf][rb][0]);
      gload16(Kg + (size_t)(kt + rb + 8 + r8) * (NKVH * HD) + (j8 ^ r8) * 8, &Ks[buf][rb + 8][0]);
    } else {
      gload16(Vg + (size_t)(rb + r8)     * S_LEN + kt + (j8 ^ r8) * 8, &Vs[buf][rb][0]);
      gload16(Vg + (size_t)(rb + 8 + r8) * S_LEN + kt + (j8 ^ r8) * 8, &Vs[buf][rb + 8][0]);
    }
  };
  auto ldK = [&](int buf, int row, int cidx) -> bf16x8_t {
    return *(const bf16x8_t*)&Ks[buf][row][(cidx ^ (row & 7)) * 8];
  };
  auto ldV = [&](int buf, int row, int cidx) -> bf16x8_t {
    return *(const bf16x8_t*)&Vs[buf][row][(cidx ^ (row & 7)) * 8];
  };

  stage(0, 0);
  __syncthreads();
  int cur = 0;
  const int NT = 4 * qt + 4;
  for (int t = 0; t < NT; ++t) {
    const int kt = t * 64;
    if (t + 1 < NT) stage(cur ^ 1, kt + 64);   // prefetch overlaps this tile's compute

    // kt - wbase is a multiple of 32 => both subtiles share the active condition
    if (kt <= wbase) {
#pragma unroll
      for (int s = 0; s < 2; ++s) {
        const int base_s = wbase + s * 16;

        // QK^T swapped: rows = keys, col = q = fr
        f32x4 sc[4];
#pragma unroll
        for (int c = 0; c < 4; ++c) {
          const int krow = c * 16 + fr;
          bf16x8_t k0 = ldK(cur, krow, fg);
          bf16x8_t k1 = ldK(cur, krow, 4 + fg);
          sc[c] = __builtin_amdgcn_mfma_f32_16x16x32_bf16(k0, qf[s][0], fz, 0, 0, 0);
          sc[c] = __builtin_amdgcn_mfma_f32_16x16x32_bf16(k1, qf[s][1], sc[c], 0, 0, 0);
        }

        // raw-domain max over own 16 keys (mask only in diagonal-crossing tiles)
        float p[4][4];
        float tm = -3.0e38f;
        if (kt + 63 > base_s) {
#pragma unroll
          for (int c = 0; c < 4; ++c)
#pragma unroll
            for (int r = 0; r < 4; ++r) {
              float v = sc[c][r];
              if (kt + c * 16 + fg * 4 + r > base_s + fr) v = -3.0e38f;
              p[c][r] = v; tm = fmaxf(tm, v);
            }
        } else {
#pragma unroll
          for (int c = 0; c < 4; ++c)
#pragma unroll
            for (int r = 0; r < 4; ++r) { p[c][r] = sc[c][r]; tm = fmaxf(tm, sc[c][r]); }
        }
        tm = fmaxf(tm, __shfl_xor(tm, 16));
        tm = fmaxf(tm, __shfl_xor(tm, 32));   // uniform across fg for each q=fr

        // defer-max: rescale only when the max actually grew past threshold
        if (!__all(tm <= m_[s] + THRRAW)) {
          const float mnew = fmaxf(m_[s], tm);
          const float sf = exp2f((m_[s] - mnew) * CEXP);
          m_[s] = mnew;
          l_[s] *= sf;
          float sfv[4];
#pragma unroll
          for (int r = 0; r < 4; ++r) sfv[r] = __shfl(sf, fg * 4 + r);
#pragma unroll
          for (int fc = 0; fc < 4; ++fc)
#pragma unroll
            for (int r = 0; r < 4; ++r) acc[s][fc][r] *= sfv[r];
        }

        // p = exp2((raw - m) * SCALE*log2e); per-lane partial l
        float ts = 0.f;
#pragma unroll
        for (int c = 0; c < 4; ++c)
#pragma unroll
          for (int r = 0; r < 4; ++r) {
            p[c][r] = exp2f((p[c][r] - m_[s]) * CEXP);
            ts += p[c][r];
          }
        l_[s] += ts;

        // P -> per-wave LDS [q][key] (reused across subtiles; per-wave LDS is in-order)
#pragma unroll
        for (int c = 0; c < 4; ++c) {
          __hip_bfloat16 b0 = __float2bfloat16(p[c][0]);
          __hip_bfloat16 b1 = __float2bfloat16(p[c][1]);
          __hip_bfloat16 b2 = __float2bfloat16(p[c][2]);
          __hip_bfloat16 b3 = __float2bfloat16(p[c][3]);
          ushort4 pk;
          pk.x = *(unsigned short*)&b0; pk.y = *(unsigned short*)&b1;
          pk.z = *(unsigned short*)&b2; pk.w = *(unsigned short*)&b3;
          *(ushort4*)&Ps[w][fr][c * 16 + fg * 4] = pk;
        }

        // PV: A = P (row q = fr), B = V (col d = fr)
#pragma unroll
        for (int kk = 0; kk < 2; ++kk) {
          bf16x8_t pa = *(const bf16x8_t*)&Ps[w][fr][kk * 32 + fg * 8];
#pragma unroll
          for (int fc = 0; fc < 4; ++fc) {
            bf16x8_t vf = ldV(cur, fc * 16 + fr, kk * 4 + fg);
            acc[s][fc] = __builtin_amdgcn_mfma_f32_16x16x32_bf16(pa, vf, acc[s][fc], 0, 0, 0);
          }
        }
      }
    }

    __syncthreads();   // prefetch landed; all waves done with buf[cur]
    cur ^= 1;
  }

  // epilogue: finish l reduce (across fg), then normalize
#pragma unroll
  for (int s = 0; s < 2; ++s) {
    float l = l_[s];
    l += __shfl_xor(l, 16);
    l += __shfl_xor(l, 32);
    float lv[4];
#pragma unroll
    for (int r = 0; r < 4; ++r) lv[r] = __builtin_amdgcn_rcpf(__shfl(l, fg * 4 + r));
#pragma unroll
    for (int fc = 0; fc < 4; ++fc)
#pragma unroll
      for (int r = 0; r < 4; ++r) {
        const size_t row = (size_t)(b * S_LEN + wbase + s * 16 + fg * 4 + r);
        O[row * DMODEL + h * HD + fc * 16 + fr] = __float2bfloat16(acc[s][fc][r] * lv[r]);
      }
  }
}

// ---------------------------------------------------------------- launch
extern "C" void kernel_launch(void* const* d_in, const int* in_sizes, int n_in,
                              void* d_out, int out_size, void* d_ws, size_t ws_size,
                              hipStream_t stream)
{
  const float* x    = (const float*)d_in[0];
  const float* cosb = (const float*)d_in[1];
  const float* sinb = (const float*)d_in[2];
  const float* Wq   = (const float*)d_in[3];
  const float* Wk   = (const float*)d_in[4];
  const float* Wv   = (const float*)d_in[5];
  const float* Wo   = (const float*)d_in[6];
  float* out = (float*)d_out;

  char* p = (char*)d_ws;
  __hip_bfloat16* x_bf    = (__hip_bfloat16*)p; p += (size_t)NB * S_LEN * DMODEL * 2;
  __hip_bfloat16* Wq_bf   = (__hip_bfloat16*)p; p += (size_t)NH * HD * DMODEL * 2;
  __hip_bfloat16* Wk_bf   = (__hip_bfloat16*)p; p += (size_t)NKVH * HD * DMODEL * 2;
  __hip_bfloat16* Wv_bf   = (__hip_bfloat16*)p; p += (size_t)NKVH * HD * DMODEL * 2;
  __hip_bfloat16* Wo_bf   = (__hip_bfloat16*)p; p += (size_t)DMODEL * NH * HD * 2;
  __hip_bfloat16* Q_bf    = (__hip_bfloat16*)p; p += (size_t)NB * S_LEN * NH * HD * 2;
  __hip_bfloat16* K_bf    = (__hip_bfloat16*)p; p += (size_t)NB * S_LEN * NKVH * HD * 2;
  __hip_bfloat16* Vt_bf   = (__hip_bfloat16*)p; p += (size_t)NB * NKVH * HD * S_LEN * 2;
  __hip_bfloat16* attn_bf = (__hip_bfloat16*)p; p += (size_t)NB * S_LEN * NH * HD * 2;

  CvtArgs ca;
  ca.s[0] = { x,  x_bf,  (int)((size_t)NB * S_LEN * DMODEL / 4) };
  ca.s[1] = { Wq, Wq_bf, (int)((size_t)NH * HD * DMODEL / 4) };
  ca.s[2] = { Wk, Wk_bf, (int)((size_t)NKVH * HD * DMODEL / 4) };
  ca.s[3] = { Wv, Wv_bf, (int)((size_t)NKVH * HD * DMODEL / 4) };
  ca.s[4] = { Wo, Wo_bf, (int)((size_t)DMODEL * NH * HD / 4) };
  int total4 = ca.s[0].n4 + ca.s[1].n4 + ca.s[2].n4 + ca.s[3].n4 + ca.s[4].n4;
  cvt_all<<<(total4 + 255) / 256, 256, 0, stream>>>(ca);

  gemm_qkv<<<dim3(3072 / 128, (NB * S_LEN) / 128), dim3(256), 0, stream>>>(
      x_bf, Wq_bf, Wk_bf, Wv_bf, Q_bf, K_bf, Vt_bf, cosb, sinb);

  attn_kernel<<<dim3(S_LEN / 256, NB * NH), dim3(512), 0, stream>>>(Q_bf, K_bf, Vt_bf, attn_bf);

  gemm_o<<<dim3(DMODEL / 128, (NB * S_LEN) / 128), dim3(256), 0, stream>>>(attn_bf, Wo_bf, out);
}